// Round 14
// baseline (1788.153 us; speedup 1.0000x reference)
//
#include <hip/hip_runtime.h>
#include <cstddef>

#define N_NODES 100000
#define N_EDGES 1600000
#define F_IN 500
#define HID 128
#define N_CLASSES 16
#define SCAN_NB ((N_NODES + 511) / 512)   // 196

// ---------------------------------------------------------------------------
// degree histogram (int): deg[dst] += 1 over edges (self-loop +1 added later)
// ---------------------------------------------------------------------------
__global__ __launch_bounds__(256) void count_deg_k(const int* __restrict__ dst,
                                                   int* __restrict__ deg) {
  int i = blockIdx.x * 256 + threadIdx.x;
  if (i < N_EDGES) atomicAdd(&deg[dst[i]], 1);
}

__global__ __launch_bounds__(256) void dinv_k(const int* __restrict__ deg,
                                              float* __restrict__ dinv) {
  int i = blockIdx.x * 256 + threadIdx.x;
  if (i < N_NODES) dinv[i] = rsqrtf((float)deg[i] + 1.0f);  // +1 = self-loop
}

// ---------------------------------------------------------------------------
// exclusive scan of deg -> rowptr (3 phases)
// ---------------------------------------------------------------------------
__global__ __launch_bounds__(512) void scan1_k(const int* __restrict__ deg,
                                               int* __restrict__ part,
                                               int* __restrict__ bsum) {
  __shared__ int tmp[512];
  const int tid = threadIdx.x;
  const int idx = blockIdx.x * 512 + tid;
  tmp[tid] = (idx < N_NODES) ? deg[idx] : 0;
  __syncthreads();
#pragma unroll
  for (int off = 1; off < 512; off <<= 1) {
    int t = (tid >= off) ? tmp[tid - off] : 0;
    __syncthreads();
    tmp[tid] += t;
    __syncthreads();
  }
  if (idx < N_NODES) part[idx] = tmp[tid];          // inclusive within block
  if (tid == 511) bsum[blockIdx.x] = tmp[511];
}

__global__ __launch_bounds__(256) void scan2_k(int* __restrict__ bsum) {
  __shared__ int tmp[256];
  const int tid = threadIdx.x;
  tmp[tid] = (tid < SCAN_NB) ? bsum[tid] : 0;
  __syncthreads();
#pragma unroll
  for (int off = 1; off < 256; off <<= 1) {
    int t = (tid >= off) ? tmp[tid - off] : 0;
    __syncthreads();
    tmp[tid] += t;
    __syncthreads();
  }
  if (tid < SCAN_NB) bsum[tid] = (tid == 0) ? 0 : tmp[tid - 1];  // exclusive block offset
}

__global__ __launch_bounds__(512) void scan3_k(const int* __restrict__ deg,
                                               const int* __restrict__ part,
                                               const int* __restrict__ bsum,
                                               int* __restrict__ rowptr,
                                               int* __restrict__ wofs) {
  const int idx = blockIdx.x * 512 + threadIdx.x;
  if (idx < N_NODES) {
    int ex = part[idx] - deg[idx] + bsum[blockIdx.x];
    rowptr[idx] = ex;
    wofs[idx] = ex;
  }
}

// ---------------------------------------------------------------------------
// bucket edges into CSR order (dst-sorted src list)
// ---------------------------------------------------------------------------
__global__ __launch_bounds__(256) void fill_k(const int* __restrict__ src,
                                              const int* __restrict__ dst,
                                              int* __restrict__ wofs,
                                              int* __restrict__ csr_src) {
  int e = blockIdx.x * 256 + threadIdx.x;
  if (e < N_EDGES) {
    int d = dst[e];
    int pos = atomicAdd(&wofs[d], 1);
    csr_src[pos] = src[e];
  }
}

// ---------------------------------------------------------------------------
// CSR aggregation, fused self-loop + bias + relu:
// out[d][:] = relu( dinv_d*( dinv_d*h[d][:] + sum_j dinv_sj*h[src_j][:] ) + b[:] )
// 32 lanes per node (one float4 each), 8 nodes per 256-thread block.
// ---------------------------------------------------------------------------
__global__ __launch_bounds__(256) void agg_k(const float* __restrict__ h,
                                             const int* __restrict__ rowptr,
                                             const int* __restrict__ deg,
                                             const int* __restrict__ csr_src,
                                             const float* __restrict__ dinv,
                                             const float* __restrict__ bias,
                                             float* __restrict__ out) {
  const int node = blockIdx.x * 8 + (threadIdx.x >> 5);
  if (node >= N_NODES) return;
  const int lane = threadIdx.x & 31;
  const float4* h4 = (const float4*)h;

  const float dd = dinv[node];
  float4 a = h4[(size_t)node * 32 + lane];
  float4 acc = make_float4(a.x * dd, a.y * dd, a.z * dd, a.w * dd);

  const int beg = rowptr[node];
  const int n = deg[node];
  for (int j = 0; j < n; ++j) {
    const int sidx = csr_src[beg + j];
    const float w = dinv[sidx];
    float4 v = h4[(size_t)sidx * 32 + lane];
    acc.x += w * v.x;
    acc.y += w * v.y;
    acc.z += w * v.z;
    acc.w += w * v.w;
  }
  const float4 b4 = ((const float4*)bias)[lane];
  acc.x = fmaxf(acc.x * dd + b4.x, 0.0f);
  acc.y = fmaxf(acc.y * dd + b4.y, 0.0f);
  acc.z = fmaxf(acc.z * dd + b4.z, 0.0f);
  acc.w = fmaxf(acc.w * dd + b4.w, 0.0f);
  ((float4*)out)[(size_t)node * 32 + lane] = acc;
}

// ---------------------------------------------------------------------------
// f32 tile GEMM, N fixed at 128. C[M,128] = A[M,K] * W[K,128]
// 128x128 block tile, 256 threads, 8x8 outputs/thread, K-step 16.
// A staged transposed (xs[kk][row], pad 129) so fragment reads are
// contiguous float4, broadcast across tx, conflict-free.
// ---------------------------------------------------------------------------
__global__ __launch_bounds__(256) void gemm_n128(const float* __restrict__ A,
                                                 const float* __restrict__ W,
                                                 float* __restrict__ C,
                                                 int M, int K, int lda) {
  __shared__ float xs[16][129];   // A^T tile: [kk][row]
  __shared__ float ws[16][128];   // B tile:   [kk][col]
  const int tid = threadIdx.x;
  const int r0 = blockIdx.x * 128;
  const int tx = tid & 15;   // cols tx*8 .. tx*8+7
  const int ty = tid >> 4;   // rows ty*8 .. ty*8+7

  float acc[8][8];
#pragma unroll
  for (int i = 0; i < 8; ++i)
#pragma unroll
    for (int j = 0; j < 8; ++j) acc[i][j] = 0.0f;

  for (int k0 = 0; k0 < K; k0 += 16) {
    // stage A tile: 128 rows x 16 kk (transposed into LDS), 8 elems/thread
#pragma unroll
    for (int l = 0; l < 8; ++l) {
      int idx = tid + l * 256;          // 0..2047
      int r = idx >> 4, kk = idx & 15;  // 16 consecutive lanes = one row's 16 k
      int gr = r0 + r, gk = k0 + kk;
      xs[kk][r] = (gr < M && gk < K) ? A[(size_t)gr * lda + gk] : 0.0f;
    }
    // stage B tile 16x128, coalesced
#pragma unroll
    for (int l = 0; l < 8; ++l) {
      int idx = tid + l * 256;
      int kk = idx >> 7, c = idx & 127;
      int gk = k0 + kk;
      ws[kk][c] = (gk < K) ? W[(size_t)gk * 128 + c] : 0.0f;
    }
    __syncthreads();
#pragma unroll
    for (int kk = 0; kk < 16; ++kk) {
      float a_[8], b_[8];
      *(float4*)&a_[0] = *(const float4*)&xs[kk][ty * 8];
      *(float4*)&a_[4] = *(const float4*)&xs[kk][ty * 8 + 4];
      *(float4*)&b_[0] = *(const float4*)&ws[kk][tx * 8];
      *(float4*)&b_[4] = *(const float4*)&ws[kk][tx * 8 + 4];
#pragma unroll
      for (int i = 0; i < 8; ++i)
#pragma unroll
        for (int j = 0; j < 8; ++j) acc[i][j] += a_[i] * b_[j];
    }
    __syncthreads();
  }
#pragma unroll
  for (int i = 0; i < 8; ++i) {
    int row = r0 + ty * 8 + i;
    if (row < M) {
      float4 v0 = make_float4(acc[i][0], acc[i][1], acc[i][2], acc[i][3]);
      float4 v1 = make_float4(acc[i][4], acc[i][5], acc[i][6], acc[i][7]);
      *(float4*)&C[(size_t)row * 128 + tx * 8] = v0;
      *(float4*)&C[(size_t)row * 128 + tx * 8 + 4] = v1;
    }
  }
}

// ---------------------------------------------------------------------------
// logits = h @ Wfc + bfc ; softmax over 16 classes. 16 rows per block.
// ---------------------------------------------------------------------------
__global__ __launch_bounds__(256) void fc_softmax_k(const float* __restrict__ h,
                                                    const float* __restrict__ Wfc,
                                                    const float* __restrict__ bfc,
                                                    float* __restrict__ out) {
  __shared__ float wsh[128 * 16];
  __shared__ float hsh[16][129];
  const int tid = threadIdx.x;
  const int r0 = blockIdx.x * 16;
#pragma unroll
  for (int l = 0; l < 8; ++l) wsh[tid + l * 256] = Wfc[tid + l * 256];
#pragma unroll
  for (int l = 0; l < 8; ++l) {
    int idx = tid + l * 256;
    int r = idx >> 7, k = idx & 127;
    hsh[r][k] = h[(size_t)(r0 + r) * 128 + k];
  }
  __syncthreads();
  const int r = tid >> 4;
  const int c = tid & 15;
  float acc = bfc[c];
#pragma unroll
  for (int k = 0; k < 128; ++k) acc += hsh[r][k] * wsh[k * 16 + c];
  float m = acc;
#pragma unroll
  for (int off = 1; off < 16; off <<= 1) m = fmaxf(m, __shfl_xor(m, off, 16));
  float ex = expf(acc - m);
  float s = ex;
#pragma unroll
  for (int off = 1; off < 16; off <<= 1) s += __shfl_xor(s, off, 16);
  out[(size_t)(r0 + r) * 16 + c] = ex / s;
}

// ---------------------------------------------------------------------------
extern "C" void kernel_launch(void* const* d_in, const int* in_sizes, int n_in,
                              void* d_out, int out_size, void* d_ws, size_t ws_size,
                              hipStream_t stream) {
  const float* x   = (const float*)d_in[0];
  const int*   ei  = (const int*)d_in[1];   // int32 [2, N_EDGES]
  const float* W1  = (const float*)d_in[2];
  const float* b1  = (const float*)d_in[3];
  const float* W2  = (const float*)d_in[4];
  const float* b2  = (const float*)d_in[5];
  const float* Wfc = (const float*)d_in[6];
  const float* bfc = (const float*)d_in[7];
  float* out       = (float*)d_out;

  const int* srcIdx = ei;
  const int* dstIdx = ei + N_EDGES;

  // workspace layout (4-byte units) — permanent arrays (~110.5 MB total):
  //   rowptr[128K] | deg[128K] | dinv[128K] | csr_src[E] | bufA[12.8M] | bufB[12.8M]
  // transient scan arrays (part/wofs/bsum) alias into bufB: every use completes
  // (stream-ordered) before agg_k first writes bufB.
  const size_t ws_need =
      (3 * 131072ull + N_EDGES + 2ull * N_NODES * HID) * sizeof(float);
  if (ws_size < ws_need) {
    // Workspace too small for the CSR layout: fail validation CLEANLY
    // (absmax ~O(1)) instead of overrunning d_ws and killing the container.
    hipMemsetAsync(d_out, 0, (size_t)out_size * sizeof(float), stream);
    return;
  }

  int*   wsI     = (int*)d_ws;
  int*   rowptr  = wsI;
  int*   deg     = wsI + 1 * 131072;
  float* dinv    = (float*)(wsI + 2 * 131072);
  int*   csr_src = wsI + 3 * 131072;
  float* bufA    = (float*)(wsI + 3 * 131072 + N_EDGES);
  float* bufB    = bufA + (size_t)N_NODES * HID;
  int*   part    = (int*)bufB;
  int*   wofs    = (int*)bufB + 131072;
  int*   bsum    = (int*)bufB + 2 * 131072;

  // ---- CSR build ----
  hipMemsetAsync(deg, 0, N_NODES * sizeof(int), stream);
  count_deg_k<<<(N_EDGES + 255) / 256, 256, 0, stream>>>(dstIdx, deg);
  dinv_k<<<(N_NODES + 255) / 256, 256, 0, stream>>>(deg, dinv);
  scan1_k<<<SCAN_NB, 512, 0, stream>>>(deg, part, bsum);
  scan2_k<<<1, 256, 0, stream>>>(bsum);
  scan3_k<<<SCAN_NB, 512, 0, stream>>>(deg, part, bsum, rowptr, wofs);
  fill_k<<<(N_EDGES + 255) / 256, 256, 0, stream>>>(srcIdx, dstIdx, wofs, csr_src);

  // ---- layer 1 ----
  gemm_n128<<<(N_NODES + 127) / 128, 256, 0, stream>>>(x, W1, bufA, N_NODES, F_IN, F_IN);
  agg_k<<<(N_NODES + 7) / 8, 256, 0, stream>>>(bufA, rowptr, deg, csr_src,
                                               dinv, b1, bufB);

  // ---- layer 2 ----
  gemm_n128<<<(N_NODES + 127) / 128, 256, 0, stream>>>(bufB, W2, bufA, N_NODES, HID, HID);
  agg_k<<<(N_NODES + 7) / 8, 256, 0, stream>>>(bufA, rowptr, deg, csr_src,
                                               dinv, b2, bufB);

  // ---- fc + softmax ----
  fc_softmax_k<<<N_NODES / 16, 256, 0, stream>>>(bufB, Wfc, bfc, out);
}

// Round 15
// 1070.735 us; speedup vs baseline: 1.6700x; 1.6700x over previous
//
#include <hip/hip_runtime.h>
#include <cstddef>

#define N_NODES 100000
#define N_EDGES 1600000
#define F_IN 500
#define HID 128
#define N_CLASSES 16
#define SCAN_NB ((N_NODES + 511) / 512)   // 196

// ---------------------------------------------------------------------------
// degree histogram (int): deg[dst] += 1 over edges (self-loop +1 added later)
// ---------------------------------------------------------------------------
__global__ __launch_bounds__(256) void count_deg_k(const int* __restrict__ dst,
                                                   int* __restrict__ deg) {
  int i = blockIdx.x * 256 + threadIdx.x;
  if (i < N_EDGES) atomicAdd(&deg[dst[i]], 1);
}

__global__ __launch_bounds__(256) void dinv_k(const int* __restrict__ deg,
                                              float* __restrict__ dinv) {
  int i = blockIdx.x * 256 + threadIdx.x;
  if (i < N_NODES) dinv[i] = rsqrtf((float)deg[i] + 1.0f);  // +1 = self-loop
}

// ---------------------------------------------------------------------------
// exclusive scan of deg -> rowptr (3 phases)
// ---------------------------------------------------------------------------
__global__ __launch_bounds__(512) void scan1_k(const int* __restrict__ deg,
                                               int* __restrict__ part,
                                               int* __restrict__ bsum) {
  __shared__ int tmp[512];
  const int tid = threadIdx.x;
  const int idx = blockIdx.x * 512 + tid;
  tmp[tid] = (idx < N_NODES) ? deg[idx] : 0;
  __syncthreads();
#pragma unroll
  for (int off = 1; off < 512; off <<= 1) {
    int t = (tid >= off) ? tmp[tid - off] : 0;
    __syncthreads();
    tmp[tid] += t;
    __syncthreads();
  }
  if (idx < N_NODES) part[idx] = tmp[tid];          // inclusive within block
  if (tid == 511) bsum[blockIdx.x] = tmp[511];
}

__global__ __launch_bounds__(256) void scan2_k(int* __restrict__ bsum) {
  __shared__ int tmp[256];
  const int tid = threadIdx.x;
  tmp[tid] = (tid < SCAN_NB) ? bsum[tid] : 0;
  __syncthreads();
#pragma unroll
  for (int off = 1; off < 256; off <<= 1) {
    int t = (tid >= off) ? tmp[tid - off] : 0;
    __syncthreads();
    tmp[tid] += t;
    __syncthreads();
  }
  if (tid < SCAN_NB) bsum[tid] = (tid == 0) ? 0 : tmp[tid - 1];  // exclusive block offset
}

__global__ __launch_bounds__(512) void scan3_k(const int* __restrict__ deg,
                                               const int* __restrict__ part,
                                               const int* __restrict__ bsum,
                                               int* __restrict__ rowptr,
                                               int* __restrict__ wofs) {
  const int idx = blockIdx.x * 512 + threadIdx.x;
  if (idx < N_NODES) {
    int ex = part[idx] - deg[idx] + bsum[blockIdx.x];
    rowptr[idx] = ex;
    wofs[idx] = ex;
  }
}

// ---------------------------------------------------------------------------
// bucket edges into CSR order (dst-sorted src list)
// ---------------------------------------------------------------------------
__global__ __launch_bounds__(256) void fill_k(const int* __restrict__ src,
                                              const int* __restrict__ dst,
                                              int* __restrict__ wofs,
                                              int* __restrict__ csr_src) {
  int e = blockIdx.x * 256 + threadIdx.x;
  if (e < N_EDGES) {
    int d = dst[e];
    int pos = atomicAdd(&wofs[d], 1);
    csr_src[pos] = src[e];
  }
}

// ---------------------------------------------------------------------------
// CSR aggregation, fused self-loop + bias + relu:
// out[d][:] = relu( dinv_d*( dinv_d*h[d][:] + sum_j dinv_sj*h[src_j][:] ) + b[:] )
// 32 lanes per node (one float4 each), 8 nodes per 256-thread block.
// ---------------------------------------------------------------------------
__global__ __launch_bounds__(256) void agg_k(const float* __restrict__ h,
                                             const int* __restrict__ rowptr,
                                             const int* __restrict__ deg,
                                             const int* __restrict__ csr_src,
                                             const float* __restrict__ dinv,
                                             const float* __restrict__ bias,
                                             float* __restrict__ out) {
  const int node = blockIdx.x * 8 + (threadIdx.x >> 5);
  if (node >= N_NODES) return;
  const int lane = threadIdx.x & 31;
  const float4* h4 = (const float4*)h;

  const float dd = dinv[node];
  float4 a = h4[(size_t)node * 32 + lane];
  float4 acc = make_float4(a.x * dd, a.y * dd, a.z * dd, a.w * dd);

  const int beg = rowptr[node];
  const int n = deg[node];
  for (int j = 0; j < n; ++j) {
    const int sidx = csr_src[beg + j];
    const float w = dinv[sidx];
    float4 v = h4[(size_t)sidx * 32 + lane];
    acc.x += w * v.x;
    acc.y += w * v.y;
    acc.z += w * v.z;
    acc.w += w * v.w;
  }
  const float4 b4 = ((const float4*)bias)[lane];
  acc.x = fmaxf(acc.x * dd + b4.x, 0.0f);
  acc.y = fmaxf(acc.y * dd + b4.y, 0.0f);
  acc.z = fmaxf(acc.z * dd + b4.z, 0.0f);
  acc.w = fmaxf(acc.w * dd + b4.w, 0.0f);
  ((float4*)out)[(size_t)node * 32 + lane] = acc;
}

// ---------------------------------------------------------------------------
// guarded float4 loaders for GEMM staging
// ---------------------------------------------------------------------------
__device__ __forceinline__ float4 ldA4(const float* __restrict__ A, int M, int K,
                                       int lda, int gr, int gk) {
  if (gr >= M) return make_float4(0.f, 0.f, 0.f, 0.f);
  if (gk + 3 < K) return *(const float4*)&A[(size_t)gr * lda + gk];
  float t0 = (gk + 0 < K) ? A[(size_t)gr * lda + gk + 0] : 0.f;
  float t1 = (gk + 1 < K) ? A[(size_t)gr * lda + gk + 1] : 0.f;
  float t2 = (gk + 2 < K) ? A[(size_t)gr * lda + gk + 2] : 0.f;
  float t3 = (gk + 3 < K) ? A[(size_t)gr * lda + gk + 3] : 0.f;
  return make_float4(t0, t1, t2, t3);
}

__device__ __forceinline__ float4 ldB4(const float* __restrict__ W, int K,
                                       int gk, int c) {
  if (gk < K) return *(const float4*)&W[(size_t)gk * 128 + c];
  return make_float4(0.f, 0.f, 0.f, 0.f);
}

// ---------------------------------------------------------------------------
// f32 tile GEMM, N fixed at 128. C[M,128] = A[M,K] * W[K,128]
// 128x128 block tile, 256 threads, 8x8 outputs/thread, K-step 16.
// Staging: 2 float4/thread per operand + REGISTER DOUBLE-BUFFER — iter k+1's
// global loads are issued before iter k's compute, hiding HBM/L2 latency
// under the 1024-FMA compute phase (R14 showed exposed staging = 89% stall).
// A staged transposed (xs[kk][row], pad 132 keeps rows 16B-aligned).
// ---------------------------------------------------------------------------
__global__ __launch_bounds__(256) void gemm_n128(const float* __restrict__ A,
                                                 const float* __restrict__ W,
                                                 float* __restrict__ C,
                                                 int M, int K, int lda) {
  __shared__ float xs[16][132];   // A^T tile: [kk][row], 132 => 16B-aligned rows
  __shared__ float ws[16][128];   // B tile:   [kk][col]
  const int tid = threadIdx.x;
  const int r0 = blockIdx.x * 128;
  const int tx = tid & 15;   // cols tx*8 .. tx*8+7
  const int ty = tid >> 4;   // rows ty*8 .. ty*8+7

  // staging decomposition
  const int arow = tid >> 2;   // A: rows arow, arow+64
  const int ac4  = tid & 3;    //    k-float4 within 16-wide slab
  const int bkk  = tid >> 5;   // B: rows bkk, bkk+8
  const int bc4  = tid & 31;   //    col-float4 within 128-wide row

  const int nIter = (K + 15) / 16;

  float acc[8][8];
#pragma unroll
  for (int i = 0; i < 8; ++i)
#pragma unroll
    for (int j = 0; j < 8; ++j) acc[i][j] = 0.0f;

  // prefetch tile 0 into registers
  float4 pa0 = ldA4(A, M, K, lda, r0 + arow,      ac4 * 4);
  float4 pa1 = ldA4(A, M, K, lda, r0 + arow + 64, ac4 * 4);
  float4 pb0 = ldB4(W, K, bkk,     bc4 * 4);
  float4 pb1 = ldB4(W, K, bkk + 8, bc4 * 4);

  for (int it = 0; it < nIter; ++it) {
    // commit prefetched tile to LDS (A transposed)
    xs[ac4 * 4 + 0][arow]      = pa0.x;
    xs[ac4 * 4 + 1][arow]      = pa0.y;
    xs[ac4 * 4 + 2][arow]      = pa0.z;
    xs[ac4 * 4 + 3][arow]      = pa0.w;
    xs[ac4 * 4 + 0][arow + 64] = pa1.x;
    xs[ac4 * 4 + 1][arow + 64] = pa1.y;
    xs[ac4 * 4 + 2][arow + 64] = pa1.z;
    xs[ac4 * 4 + 3][arow + 64] = pa1.w;
    *(float4*)&ws[bkk][bc4 * 4]     = pb0;
    *(float4*)&ws[bkk + 8][bc4 * 4] = pb1;
    __syncthreads();

    // issue next tile's loads BEFORE compute (latency hides under FMAs)
    if (it + 1 < nIter) {
      const int k0 = (it + 1) * 16;
      pa0 = ldA4(A, M, K, lda, r0 + arow,      k0 + ac4 * 4);
      pa1 = ldA4(A, M, K, lda, r0 + arow + 64, k0 + ac4 * 4);
      pb0 = ldB4(W, K, k0 + bkk,     bc4 * 4);
      pb1 = ldB4(W, K, k0 + bkk + 8, bc4 * 4);
    }

#pragma unroll
    for (int kk = 0; kk < 16; ++kk) {
      float a_[8], b_[8];
      *(float4*)&a_[0] = *(const float4*)&xs[kk][ty * 8];
      *(float4*)&a_[4] = *(const float4*)&xs[kk][ty * 8 + 4];
      *(float4*)&b_[0] = *(const float4*)&ws[kk][tx * 8];
      *(float4*)&b_[4] = *(const float4*)&ws[kk][tx * 8 + 4];
#pragma unroll
      for (int i = 0; i < 8; ++i)
#pragma unroll
        for (int j = 0; j < 8; ++j) acc[i][j] += a_[i] * b_[j];
    }
    __syncthreads();
  }

#pragma unroll
  for (int i = 0; i < 8; ++i) {
    int row = r0 + ty * 8 + i;
    if (row < M) {
      float4 v0 = make_float4(acc[i][0], acc[i][1], acc[i][2], acc[i][3]);
      float4 v1 = make_float4(acc[i][4], acc[i][5], acc[i][6], acc[i][7]);
      *(float4*)&C[(size_t)row * 128 + tx * 8] = v0;
      *(float4*)&C[(size_t)row * 128 + tx * 8 + 4] = v1;
    }
  }
}

// ---------------------------------------------------------------------------
// logits = h @ Wfc + bfc ; softmax over 16 classes. 16 rows per block.
// ---------------------------------------------------------------------------
__global__ __launch_bounds__(256) void fc_softmax_k(const float* __restrict__ h,
                                                    const float* __restrict__ Wfc,
                                                    const float* __restrict__ bfc,
                                                    float* __restrict__ out) {
  __shared__ float wsh[128 * 16];
  __shared__ float hsh[16][129];
  const int tid = threadIdx.x;
  const int r0 = blockIdx.x * 16;
#pragma unroll
  for (int l = 0; l < 8; ++l) wsh[tid + l * 256] = Wfc[tid + l * 256];
#pragma unroll
  for (int l = 0; l < 8; ++l) {
    int idx = tid + l * 256;
    int r = idx >> 7, k = idx & 127;
    hsh[r][k] = h[(size_t)(r0 + r) * 128 + k];
  }
  __syncthreads();
  const int r = tid >> 4;
  const int c = tid & 15;
  float acc = bfc[c];
#pragma unroll
  for (int k = 0; k < 128; ++k) acc += hsh[r][k] * wsh[k * 16 + c];
  float m = acc;
#pragma unroll
  for (int off = 1; off < 16; off <<= 1) m = fmaxf(m, __shfl_xor(m, off, 16));
  float ex = expf(acc - m);
  float s = ex;
#pragma unroll
  for (int off = 1; off < 16; off <<= 1) s += __shfl_xor(s, off, 16);
  out[(size_t)(r0 + r) * 16 + c] = ex / s;
}

// ---------------------------------------------------------------------------
extern "C" void kernel_launch(void* const* d_in, const int* in_sizes, int n_in,
                              void* d_out, int out_size, void* d_ws, size_t ws_size,
                              hipStream_t stream) {
  const float* x   = (const float*)d_in[0];
  const int*   ei  = (const int*)d_in[1];   // int32 [2, N_EDGES]
  const float* W1  = (const float*)d_in[2];
  const float* b1  = (const float*)d_in[3];
  const float* W2  = (const float*)d_in[4];
  const float* b2  = (const float*)d_in[5];
  const float* Wfc = (const float*)d_in[6];
  const float* bfc = (const float*)d_in[7];
  float* out       = (float*)d_out;

  const int* srcIdx = ei;
  const int* dstIdx = ei + N_EDGES;

  // workspace layout (4-byte units) — permanent arrays (~110.5 MB total):
  //   rowptr[128K] | deg[128K] | dinv[128K] | csr_src[E] | bufA[12.8M] | bufB[12.8M]
  // transient scan arrays (part/wofs/bsum) alias into bufB: every use completes
  // (stream-ordered) before agg_k first writes bufB.
  const size_t ws_need =
      (3 * 131072ull + N_EDGES + 2ull * N_NODES * HID) * sizeof(float);
  if (ws_size < ws_need) {
    // Workspace too small for the CSR layout: fail validation CLEANLY
    // (absmax ~O(1)) instead of overrunning d_ws and killing the container.
    hipMemsetAsync(d_out, 0, (size_t)out_size * sizeof(float), stream);
    return;
  }

  int*   wsI     = (int*)d_ws;
  int*   rowptr  = wsI;
  int*   deg     = wsI + 1 * 131072;
  float* dinv    = (float*)(wsI + 2 * 131072);
  int*   csr_src = wsI + 3 * 131072;
  float* bufA    = (float*)(wsI + 3 * 131072 + N_EDGES);
  float* bufB    = bufA + (size_t)N_NODES * HID;
  int*   part    = (int*)bufB;
  int*   wofs    = (int*)bufB + 131072;
  int*   bsum    = (int*)bufB + 2 * 131072;

  // ---- CSR build ----
  hipMemsetAsync(deg, 0, N_NODES * sizeof(int), stream);
  count_deg_k<<<(N_EDGES + 255) / 256, 256, 0, stream>>>(dstIdx, deg);
  dinv_k<<<(N_NODES + 255) / 256, 256, 0, stream>>>(deg, dinv);
  scan1_k<<<SCAN_NB, 512, 0, stream>>>(deg, part, bsum);
  scan2_k<<<1, 256, 0, stream>>>(bsum);
  scan3_k<<<SCAN_NB, 512, 0, stream>>>(deg, part, bsum, rowptr, wofs);
  fill_k<<<(N_EDGES + 255) / 256, 256, 0, stream>>>(srcIdx, dstIdx, wofs, csr_src);

  // ---- layer 1 ----
  gemm_n128<<<(N_NODES + 127) / 128, 256, 0, stream>>>(x, W1, bufA, N_NODES, F_IN, F_IN);
  agg_k<<<(N_NODES + 7) / 8, 256, 0, stream>>>(bufA, rowptr, deg, csr_src,
                                               dinv, b1, bufB);

  // ---- layer 2 ----
  gemm_n128<<<(N_NODES + 127) / 128, 256, 0, stream>>>(bufB, W2, bufA, N_NODES, HID, HID);
  agg_k<<<(N_NODES + 7) / 8, 256, 0, stream>>>(bufA, rowptr, deg, csr_src,
                                               dinv, b2, bufB);

  // ---- fc + softmax ----
  fc_softmax_k<<<N_NODES / 16, 256, 0, stream>>>(bufB, Wfc, bfc, out);
}